// Round 5
// baseline (5378.763 us; speedup 1.0000x reference)
//
#include <hip/hip_runtime.h>
#include <hip/hip_bf16.h>
#include <math.h>

#define B_ 2
#define T_ 2048
#define C_ 1024
#define H_ 16
#define D_ 64
#define F_ 4096
#define BT_ (B_*T_)

typedef __attribute__((ext_vector_type(8))) short bf16x8;
typedef __attribute__((ext_vector_type(4))) float f32x4;

__device__ __forceinline__ float bfraw2f(unsigned int u){
    union { unsigned int i; float f; } c; c.i = u << 16; return c.f;
}
// f32 -> bf16 raw bits, round-to-nearest-even
__device__ __forceinline__ short f2bfraw(float f){
    union { float f; unsigned int i; } c; c.f = f;
    unsigned int u = c.i;
    u += 0x7fffu + ((u >> 16) & 1u);
    return (short)(u >> 16);
}

// ---------------- per-row LN stats: (mu, rsqrt(var+eps)) ----------------
// XF: 1 -> x fp32; 0 -> x bf16 (ws)
template<int XF>
__global__ __launch_bounds__(256) void stats_kernel(const void* __restrict__ x, int ld,
                                                    float2* __restrict__ out)
{
    __shared__ float sm1[4], sm2[4];
    int row = blockIdx.x;
    size_t base = (size_t)row * ld;
    int t = threadIdx.x;
    float s = 0.f, ss = 0.f;
#pragma unroll
    for (int i = 0; i < 4; i++) {
        float f = XF ? ((const float*)x)[base + i*256 + t]
                     : (float)((const __hip_bfloat16*)x)[base + i*256 + t];
        s += f; ss += f * f;
    }
#pragma unroll
    for (int off = 32; off >= 1; off >>= 1) {
        s  += __shfl_xor(s,  off);
        ss += __shfl_xor(ss, off);
    }
    int wave = t >> 6, lane = t & 63;
    if (!lane) { sm1[wave] = s; sm2[wave] = ss; }
    __syncthreads();
    if (t == 0) {
        s  = sm1[0] + sm1[1] + sm1[2] + sm1[3];
        ss = sm2[0] + sm2[1] + sm2[2] + sm2[3];
        float mu  = s * (1.f / C_);
        float var = ss * (1.f / C_) - mu * mu;
        if (var < 0.f) var = 0.f;
        out[row] = make_float2(mu, rsqrtf(var + 1e-5f));
    }
}

// ---------------- MFMA GEMM: out = op(A)[M,K] @ W[K,N] + bias (+GELU)(+res) ----
// LNA: 1 apply LN to A rows. AF: 1 A fp32 global, 0 A bf16 ws.
// ACT: 1 exact GELU. RES: 0 none, 1 fp32, 2 bf16 ws, 3 fp32 (partial d_out).
// OUTF: 0 bf16 out, 1 fp32 out. W/bias/lng/lnb always fp32.
// Tile 64x64, BK=32, 4 waves; wave w computes rows [w*16,w*16+16) x all 64 cols.
template<int LNA, int AF, int ACT, int RES, int OUTF>
__global__ __launch_bounds__(256) void gemm_mfma(
    const void* A, int lda,
    const float2* __restrict__ stats,
    const float* __restrict__ lng, const float* __restrict__ lnb,
    const float* __restrict__ W, int ldw, size_t woff,
    const float* __restrict__ bias, int boff,
    const void* res, int ldres,
    void* out, int ldo,
    int N, int K)
{
    __shared__ __align__(16) short As[64 * 40];   // As[m][k], stride 40 (pad)
    __shared__ __align__(16) short Bs[64 * 40];   // Bs[n][k], stride 40 (pad)
    int tid = threadIdx.x;
    int wave = tid >> 6, lane = tid & 63;
    int quad = lane >> 4, l16 = lane & 15;
    int m0 = blockIdx.y * 64, n0 = blockIdx.x * 64;

    // A staging role: row = tid>>2 (64 rows), kq = (tid&3)*8
    int ar = tid >> 2, akq = (tid & 3) * 8;
    // B staging role: k_row = tid>>3 (32 rows), bn0 = (tid&7)*8
    int bk = tid >> 3, bn0 = (tid & 7) * 8;

    f32x4 acc[4];
#pragma unroll
    for (int t = 0; t < 4; t++) acc[t] = (f32x4){0.f, 0.f, 0.f, 0.f};

    for (int k0 = 0; k0 < K; k0 += 32) {
        // ---- stage A tile [64 x 32] ----
        {
            float a[8];
            if (AF) {
                const float* pa = (const float*)A + (size_t)(m0 + ar) * lda + k0 + akq;
                float4 u0 = *(const float4*)pa;
                float4 u1 = *(const float4*)(pa + 4);
                a[0]=u0.x; a[1]=u0.y; a[2]=u0.z; a[3]=u0.w;
                a[4]=u1.x; a[5]=u1.y; a[6]=u1.z; a[7]=u1.w;
            } else {
                const __hip_bfloat16* pa = (const __hip_bfloat16*)A + (size_t)(m0 + ar) * lda + k0 + akq;
                uint4 u = *(const uint4*)pa;
                unsigned int w4[4] = {u.x, u.y, u.z, u.w};
#pragma unroll
                for (int i = 0; i < 4; i++) {
                    a[2*i]   = bfraw2f(w4[i] & 0xffffu);
                    a[2*i+1] = bfraw2f(w4[i] >> 16);
                }
            }
            short pk[8];
            if (LNA) {
                float2 st = stats[m0 + ar];
#pragma unroll
                for (int i = 0; i < 8; i++) {
                    int k = k0 + akq + i;
                    pk[i] = f2bfraw((a[i] - st.x) * st.y * lng[k] + lnb[k]);
                }
            } else {
#pragma unroll
                for (int i = 0; i < 8; i++) pk[i] = f2bfraw(a[i]);
            }
            *(bf16x8*)&As[ar * 40 + akq] = *(bf16x8*)pk;
        }
        // ---- stage W tile [32 x 64] transposed -> Bs[n][k] ----
        {
            const float* pw = W + woff + (size_t)(k0 + bk) * ldw + n0 + bn0;
            float4 w0 = *(const float4*)pw;
            float4 w1 = *(const float4*)(pw + 4);
            float wv[8] = {w0.x, w0.y, w0.z, w0.w, w1.x, w1.y, w1.z, w1.w};
#pragma unroll
            for (int u = 0; u < 8; u++)
                Bs[(bn0 + u) * 40 + bk] = f2bfraw(wv[u]);
        }
        __syncthreads();
        // ---- compute ----
        bf16x8 af = *(const bf16x8*)&As[(wave * 16 + l16) * 40 + quad * 8];
#pragma unroll
        for (int t = 0; t < 4; t++) {
            bf16x8 bfr = *(const bf16x8*)&Bs[(t * 16 + l16) * 40 + quad * 8];
            acc[t] = __builtin_amdgcn_mfma_f32_16x16x32_bf16(af, bfr, acc[t], 0, 0, 0);
        }
        __syncthreads();
    }

    // ---- epilogue: C[row][col], col = l16, row = quad*4 + reg ----
#pragma unroll
    for (int t = 0; t < 4; t++) {
        int c = n0 + t * 16 + l16;
        float bv = bias ? bias[boff + c] : 0.f;
#pragma unroll
        for (int reg = 0; reg < 4; reg++) {
            int r = m0 + wave * 16 + quad * 4 + reg;
            float v = acc[t][reg] + bv;
            if (ACT == 1) v = 0.5f * v * (1.f + erff(v * 0.70710678118654752f));
            if (RES == 1) v += ((const float*)res)[(size_t)r * ldres + c];
            if (RES == 2) v += (float)((const __hip_bfloat16*)res)[(size_t)r * ldres + c];
            if (RES == 3) v += ((const float*)res)[(size_t)r * ldres + c];
            if (OUTF) ((float*)out)[(size_t)r * ldo + c] = v;
            else ((__hip_bfloat16*)out)[(size_t)r * ldo + c] = __float2bfloat16(v);
        }
    }
}

// ---------------- Causal attention, online softmax ----------------
// qkv: [B*T, 3C] bf16 (ws), row = Q | K | V. Output -> own (dead) Q slot.
// One wave per query row.
__global__ __launch_bounds__(256) void attn_kernel(__hip_bfloat16* qkv)
{
    __shared__ float q_lds[4][64];
    int wave = threadIdx.x >> 6, lane = threadIdx.x & 63;
    int qrow = blockIdx.x * 4 + wave;
    int h = blockIdx.y, b = blockIdx.z;
    int grow = b * T_ + qrow;
    const size_t rowstride = 3 * C_;

    const __hip_bfloat16* Qp = qkv + (size_t)grow * rowstride + h * D_;
    q_lds[wave][lane] = (float)Qp[lane] * 0.125f;   // 1/sqrt(64)
    __syncthreads();

    const __hip_bfloat16* Kbase = qkv + (size_t)b * T_ * rowstride + C_ + h * D_;
    const __hip_bfloat16* Vbase = qkv + (size_t)b * T_ * rowstride + 2 * C_ + h * D_;

    float m = -INFINITY, l = 0.f, oacc = 0.f;
    int total = qrow + 1;
    int c0 = 0;

    // ---- full 64-key chunks: compile-time trip counts, unrolled ----
    for (; c0 + 64 <= total; c0 += 64) {
        int j = c0 + lane;
        const uint4* Kp4 = (const uint4*)(Kbase + (size_t)j * rowstride);
        float s = 0.f;
#pragma unroll
        for (int v8 = 0; v8 < 8; v8++) {
            uint4 u = Kp4[v8];
            const float* qq = &q_lds[wave][v8 * 8];
            s = fmaf(qq[0], bfraw2f(u.x & 0xffffu), s);
            s = fmaf(qq[1], bfraw2f(u.x >> 16), s);
            s = fmaf(qq[2], bfraw2f(u.y & 0xffffu), s);
            s = fmaf(qq[3], bfraw2f(u.y >> 16), s);
            s = fmaf(qq[4], bfraw2f(u.z & 0xffffu), s);
            s = fmaf(qq[5], bfraw2f(u.z >> 16), s);
            s = fmaf(qq[6], bfraw2f(u.w & 0xffffu), s);
            s = fmaf(qq[7], bfraw2f(u.w >> 16), s);
        }
        float mc = s;
#pragma unroll
        for (int off = 32; off >= 1; off >>= 1) mc = fmaxf(mc, __shfl_xor(mc, off));
        float mn = fmaxf(m, mc);
        float alpha = (m == -INFINITY) ? 0.f : __expf(m - mn);
        float p = __expf(s - mn);
        float psum = p;
#pragma unroll
        for (int off = 32; off >= 1; off >>= 1) psum += __shfl_xor(psum, off);
        l = l * alpha + psum;
        oacc *= alpha;
        const __hip_bfloat16* Vc = Vbase + (size_t)c0 * rowstride + lane;
#pragma unroll
        for (int jj0 = 0; jj0 < 64; jj0 += 16) {
            float vv[16];
#pragma unroll
            for (int u = 0; u < 16; u++)
                vv[u] = (float)Vc[(size_t)(jj0 + u) * rowstride];
#pragma unroll
            for (int u = 0; u < 16; u++)
                oacc = fmaf(__shfl(p, jj0 + u), vv[u], oacc);
        }
        m = mn;
    }

    // ---- tail chunk (dynamic 1..63 keys) ----
    if (c0 < total) {
        int kmax = total - c0;
        int j = c0 + lane;
        float s = -INFINITY;
        if (lane < kmax) {
            const uint4* Kp4 = (const uint4*)(Kbase + (size_t)j * rowstride);
            float acc = 0.f;
#pragma unroll
            for (int v8 = 0; v8 < 8; v8++) {
                uint4 u = Kp4[v8];
                const float* qq = &q_lds[wave][v8 * 8];
                acc = fmaf(qq[0], bfraw2f(u.x & 0xffffu), acc);
                acc = fmaf(qq[1], bfraw2f(u.x >> 16), acc);
                acc = fmaf(qq[2], bfraw2f(u.y & 0xffffu), acc);
                acc = fmaf(qq[3], bfraw2f(u.y >> 16), acc);
                acc = fmaf(qq[4], bfraw2f(u.z & 0xffffu), acc);
                acc = fmaf(qq[5], bfraw2f(u.z >> 16), acc);
                acc = fmaf(qq[6], bfraw2f(u.w & 0xffffu), acc);
                acc = fmaf(qq[7], bfraw2f(u.w >> 16), acc);
            }
            s = acc;
        }
        float mc = s;
#pragma unroll
        for (int off = 32; off >= 1; off >>= 1) mc = fmaxf(mc, __shfl_xor(mc, off));
        float mn = fmaxf(m, mc);
        float alpha = (m == -INFINITY) ? 0.f : __expf(m - mn);
        float p = (lane < kmax) ? __expf(s - mn) : 0.f;
        float psum = p;
#pragma unroll
        for (int off = 32; off >= 1; off >>= 1) psum += __shfl_xor(psum, off);
        l = l * alpha + psum;
        oacc *= alpha;
        const __hip_bfloat16* Vc = Vbase + (size_t)c0 * rowstride + lane;
        for (int jj = 0; jj < kmax; jj++) {
            float pj = __shfl(p, jj);
            float v = (float)Vc[(size_t)jj * rowstride];
            oacc = fmaf(pj, v, oacc);
        }
        m = mn;
    }

    qkv[(size_t)grow * rowstride + h * D_ + lane] = __float2bfloat16(oacc / l);
}

extern "C" void kernel_launch(void* const* d_in, const int* in_sizes, int n_in,
                              void* d_out, int out_size, void* d_ws, size_t ws_size,
                              hipStream_t stream)
{
    const float* x     = (const float*)d_in[0];
    const float* ln1_g = (const float*)d_in[1];
    const float* ln1_b = (const float*)d_in[2];
    const float* qkv_w = (const float*)d_in[3];
    const float* qkv_b = (const float*)d_in[4];
    const float* out_w = (const float*)d_in[5];
    const float* out_b = (const float*)d_in[6];
    const float* ln2_g = (const float*)d_in[7];
    const float* ln2_b = (const float*)d_in[8];
    const float* ff1_w = (const float*)d_in[9];
    const float* ff1_b = (const float*)d_in[10];
    const float* ff2_w = (const float*)d_in[11];
    const float* ff2_b = (const float*)d_in[12];

    // ws layout (24 MiB + 64 KiB):
    //   [0, 24M)   qkv bf16 [4096,3072]; Q slots: q->attn-out->ff1 act,
    //              K slots: k->ff1 act, V slots: v->x1 residual
    //   [24M, +32K)  stats1 ; [24M+32K, +32K) stats2
    char* ws = (char*)d_ws;
    __hip_bfloat16* qkv = (__hip_bfloat16*)ws;
    float2* S1 = (float2*)(ws + 25165824);
    float2* S2 = (float2*)(ws + 25165824 + 32768);
    __hip_bfloat16* x1  = qkv + 2048;               // V slots, ld = 3072

    // 1) LN1 stats on x
    stats_kernel<1><<<BT_, 256, 0, stream>>>(x, C_, S1);
    // 2) QKV: LN1(x) @ qkv_w + qkv_b -> qkv (bf16)
    {
        dim3 g(3 * C_ / 64, BT_ / 64);
        gemm_mfma<1,1,0,0,0><<<g, 256, 0, stream>>>(
            x, C_, S1, ln1_g, ln1_b, qkv_w, 3 * C_, 0, qkv_b, 0,
            nullptr, 0, qkv, 3 * C_, 3 * C_, C_);
    }
    // 3) attention -> Q slots
    {
        dim3 g(T_ / 4, H_, B_);
        attn_kernel<<<g, 256, 0, stream>>>(qkv);
    }
    // 4) out proj + residual(x fp32) -> x1 (V slots, bf16)
    {
        dim3 g(C_ / 64, BT_ / 64);
        gemm_mfma<0,0,0,1,0><<<g, 256, 0, stream>>>(
            qkv, 3 * C_, nullptr, nullptr, nullptr, out_w, C_, 0, out_b, 0,
            x, C_, x1, 3 * C_, C_, C_);
    }
    // 5) LN2 stats on x1 (bf16, ld 3072)
    stats_kernel<0><<<BT_, 256, 0, stream>>>(x1, 3 * C_, S2);
    // 6) FF in two K-chunks of 2048; act chunk in Q+K slots (cols 0..2047)
    for (int f = 0; f < 2; f++) {
        {   // FF1 chunk: LN2(x1) @ ff1_w[:, f*2048:+2048] + b, GELU -> qkv cols 0..2047
            dim3 g(2048 / 64, BT_ / 64);
            gemm_mfma<1,0,1,0,0><<<g, 256, 0, stream>>>(
                x1, 3 * C_, S2, ln2_g, ln2_b, ff1_w, F_, (size_t)f * 2048, ff1_b, f * 2048,
                nullptr, 0, qkv, 3 * C_, 2048, C_);
        }
        {   // FF2 chunk -> d_out fp32 (+x1 residual on f==0, +partial on f==1)
            dim3 g(C_ / 64, BT_ / 64);
            if (f == 0)
                gemm_mfma<0,0,0,2,1><<<g, 256, 0, stream>>>(
                    qkv, 3 * C_, nullptr, nullptr, nullptr, ff2_w, C_, 0,
                    ff2_b, 0, x1, 3 * C_, d_out, C_, C_, 2048);
            else
                gemm_mfma<0,0,0,3,1><<<g, 256, 0, stream>>>(
                    qkv, 3 * C_, nullptr, nullptr, nullptr, ff2_w, C_, (size_t)2048 * C_,
                    nullptr, 0, d_out, C_, d_out, C_, C_, 2048);
        }
    }
}

// Round 6
// 902.946 us; speedup vs baseline: 5.9569x; 5.9569x over previous
//
#include <hip/hip_runtime.h>
#include <hip/hip_bf16.h>
#include <math.h>

#define B_ 2
#define T_ 2048
#define C_ 1024
#define H_ 16
#define D_ 64
#define F_ 4096
#define BT_ (B_*T_)

typedef __attribute__((ext_vector_type(8))) short bf16x8;
typedef __attribute__((ext_vector_type(4))) float f32x4;

__device__ __forceinline__ float bfraw2f(unsigned int u){
    union { unsigned int i; float f; } c; c.i = u << 16; return c.f;
}
// f32 -> bf16 raw bits, round-to-nearest-even
__device__ __forceinline__ short f2bfraw(float f){
    union { float f; unsigned int i; } c; c.f = f;
    unsigned int u = c.i;
    u += 0x7fffu + ((u >> 16) & 1u);
    return (short)(u >> 16);
}

// ---------------- per-row LN stats: (mu, rsqrt(var+eps)) ----------------
template<int XF>
__global__ __launch_bounds__(256) void stats_kernel(const void* __restrict__ x, int ld,
                                                    float2* __restrict__ out)
{
    __shared__ float sm1[4], sm2[4];
    int row = blockIdx.x;
    size_t base = (size_t)row * ld;
    int t = threadIdx.x;
    float s = 0.f, ss = 0.f;
#pragma unroll
    for (int i = 0; i < 4; i++) {
        float f = XF ? ((const float*)x)[base + i*256 + t]
                     : (float)((const __hip_bfloat16*)x)[base + i*256 + t];
        s += f; ss += f * f;
    }
#pragma unroll
    for (int off = 32; off >= 1; off >>= 1) {
        s  += __shfl_xor(s,  off);
        ss += __shfl_xor(ss, off);
    }
    int wave = t >> 6, lane = t & 63;
    if (!lane) { sm1[wave] = s; sm2[wave] = ss; }
    __syncthreads();
    if (t == 0) {
        s  = sm1[0] + sm1[1] + sm1[2] + sm1[3];
        ss = sm2[0] + sm2[1] + sm2[2] + sm2[3];
        float mu  = s * (1.f / C_);
        float var = ss * (1.f / C_) - mu * mu;
        if (var < 0.f) var = 0.f;
        out[row] = make_float2(mu, rsqrtf(var + 1e-5f));
    }
}

// ---------------- MFMA GEMM (unchanged from R5 — passed) ----------------
template<int LNA, int AF, int ACT, int RES, int OUTF>
__global__ __launch_bounds__(256) void gemm_mfma(
    const void* A, int lda,
    const float2* __restrict__ stats,
    const float* __restrict__ lng, const float* __restrict__ lnb,
    const float* __restrict__ W, int ldw, size_t woff,
    const float* __restrict__ bias, int boff,
    const void* res, int ldres,
    void* out, int ldo,
    int N, int K)
{
    __shared__ __align__(16) short As[64 * 40];
    __shared__ __align__(16) short Bs[64 * 40];
    int tid = threadIdx.x;
    int wave = tid >> 6, lane = tid & 63;
    int quad = lane >> 4, l16 = lane & 15;
    int m0 = blockIdx.y * 64, n0 = blockIdx.x * 64;

    int ar = tid >> 2, akq = (tid & 3) * 8;
    int bk = tid >> 3, bn0 = (tid & 7) * 8;

    f32x4 acc[4];
#pragma unroll
    for (int t = 0; t < 4; t++) acc[t] = (f32x4){0.f, 0.f, 0.f, 0.f};

    for (int k0 = 0; k0 < K; k0 += 32) {
        {
            float a[8];
            if (AF) {
                const float* pa = (const float*)A + (size_t)(m0 + ar) * lda + k0 + akq;
                float4 u0 = *(const float4*)pa;
                float4 u1 = *(const float4*)(pa + 4);
                a[0]=u0.x; a[1]=u0.y; a[2]=u0.z; a[3]=u0.w;
                a[4]=u1.x; a[5]=u1.y; a[6]=u1.z; a[7]=u1.w;
            } else {
                const __hip_bfloat16* pa = (const __hip_bfloat16*)A + (size_t)(m0 + ar) * lda + k0 + akq;
                uint4 u = *(const uint4*)pa;
                unsigned int w4[4] = {u.x, u.y, u.z, u.w};
#pragma unroll
                for (int i = 0; i < 4; i++) {
                    a[2*i]   = bfraw2f(w4[i] & 0xffffu);
                    a[2*i+1] = bfraw2f(w4[i] >> 16);
                }
            }
            short pk[8];
            if (LNA) {
                float2 st = stats[m0 + ar];
#pragma unroll
                for (int i = 0; i < 8; i++) {
                    int k = k0 + akq + i;
                    pk[i] = f2bfraw((a[i] - st.x) * st.y * lng[k] + lnb[k]);
                }
            } else {
#pragma unroll
                for (int i = 0; i < 8; i++) pk[i] = f2bfraw(a[i]);
            }
            *(bf16x8*)&As[ar * 40 + akq] = *(bf16x8*)pk;
        }
        {
            const float* pw = W + woff + (size_t)(k0 + bk) * ldw + n0 + bn0;
            float4 w0 = *(const float4*)pw;
            float4 w1 = *(const float4*)(pw + 4);
            float wv[8] = {w0.x, w0.y, w0.z, w0.w, w1.x, w1.y, w1.z, w1.w};
#pragma unroll
            for (int u = 0; u < 8; u++)
                Bs[(bn0 + u) * 40 + bk] = f2bfraw(wv[u]);
        }
        __syncthreads();
        bf16x8 af = *(const bf16x8*)&As[(wave * 16 + l16) * 40 + quad * 8];
#pragma unroll
        for (int t = 0; t < 4; t++) {
            bf16x8 bfr = *(const bf16x8*)&Bs[(t * 16 + l16) * 40 + quad * 8];
            acc[t] = __builtin_amdgcn_mfma_f32_16x16x32_bf16(af, bfr, acc[t], 0, 0, 0);
        }
        __syncthreads();
    }

#pragma unroll
    for (int t = 0; t < 4; t++) {
        int c = n0 + t * 16 + l16;
        float bv = bias ? bias[boff + c] : 0.f;
#pragma unroll
        for (int reg = 0; reg < 4; reg++) {
            int r = m0 + wave * 16 + quad * 4 + reg;
            float v = acc[t][reg] + bv;
            if (ACT == 1) v = 0.5f * v * (1.f + erff(v * 0.70710678118654752f));
            if (RES == 1) v += ((const float*)res)[(size_t)r * ldres + c];
            if (RES == 2) v += (float)((const __hip_bfloat16*)res)[(size_t)r * ldres + c];
            if (RES == 3) v += ((const float*)res)[(size_t)r * ldres + c];
            if (OUTF) ((float*)out)[(size_t)r * ldo + c] = v;
            else ((__hip_bfloat16*)out)[(size_t)r * ldo + c] = __float2bfloat16(v);
        }
    }
}

// ---------------- MFMA flash attention ----------------
// qkv [B*T, 3C] bf16: Q|K|V slots. One block = 64 Q rows of one (b,h).
// Wave w handles Q rows [qb*64+w*16, +16). Iterate 64-key tiles with online
// softmax; QK^T and PV via mfma_f32_16x16x32_bf16. Output -> dead Q slot.
__global__ __launch_bounds__(256) void attn_flash(__hip_bfloat16* qkv)
{
    __shared__ __align__(16) short Vt[64 * 72];        // V^T[d][key], stride 72
    __shared__ __align__(16) short Pl[4][16 * 72];     // per-wave P[q][key]
    int tid = threadIdx.x;
    int wave = tid >> 6, lane = tid & 63;
    int quad = lane >> 4, l16 = lane & 15;
    int qb = (gridDim.x - 1) - blockIdx.x;             // big tiles first
    int h = blockIdx.y, b = blockIdx.z;
    const size_t rs = 3 * C_;
    __hip_bfloat16* base = qkv + (size_t)b * T_ * rs;
    const __hip_bfloat16* Qb = base + h * D_;
    const __hip_bfloat16* Kb = base + C_ + h * D_;
    const __hip_bfloat16* Vb = base + 2 * C_ + h * D_;
    int qbase = qb * 64 + wave * 16;

    // Q fragments: rows qbase+l16, d-chunks {0..31},{32..63}, k=quad*8+i
    bf16x8 qf0 = *(const bf16x8*)(Qb + (size_t)(qbase + l16) * rs + quad * 8);
    bf16x8 qf1 = *(const bf16x8*)(Qb + (size_t)(qbase + l16) * rs + 32 + quad * 8);

    f32x4 o[4];
#pragma unroll
    for (int t = 0; t < 4; t++) o[t] = (f32x4){0.f, 0.f, 0.f, 0.f};
    float m[4] = {-INFINITY, -INFINITY, -INFINITY, -INFINITY};
    float l[4] = {0.f, 0.f, 0.f, 0.f};

    int vkey = tid & 63, vg0 = tid >> 6;

    for (int kt = 0; kt <= qb; kt++) {
        int kb = kt * 64;
        __syncthreads();   // previous tile's Vt reads complete
        // ---- stage V^T tile ----
#pragma unroll
        for (int it = 0; it < 2; it++) {
            int d0 = (vg0 + it * 4) * 8;
            uint4 u = *(const uint4*)(Vb + (size_t)(kb + vkey) * rs + d0);
            union { uint4 v; short s[8]; } cc; cc.v = u;
#pragma unroll
            for (int u8 = 0; u8 < 8; u8++)
                Vt[(d0 + u8) * 72 + vkey] = cc.s[u8];
        }
        __syncthreads();

        // ---- S = (Q*scale) K^T : 4 key-subtiles of 16 ----
        f32x4 sa[4];
#pragma unroll
        for (int t16 = 0; t16 < 4; t16++) {
            const __hip_bfloat16* kr = Kb + (size_t)(kb + t16 * 16 + l16) * rs;
            bf16x8 kf0 = *(const bf16x8*)(kr + quad * 8);
            bf16x8 kf1 = *(const bf16x8*)(kr + 32 + quad * 8);
            f32x4 s = (f32x4){0.f, 0.f, 0.f, 0.f};
            s = __builtin_amdgcn_mfma_f32_16x16x32_bf16(qf0, kf0, s, 0, 0, 0);
            s = __builtin_amdgcn_mfma_f32_16x16x32_bf16(qf1, kf1, s, 0, 0, 0);
            sa[t16] = s;
        }
        // scale + causal mask (diagonal tile only)
#pragma unroll
        for (int t16 = 0; t16 < 4; t16++) {
#pragma unroll
            for (int reg = 0; reg < 4; reg++) {
                float v = sa[t16][reg] * 0.125f;
                if (kt == qb) {
                    int keyl = t16 * 16 + l16;
                    int ql = wave * 16 + quad * 4 + reg;
                    if (keyl > ql) v = -3.0e38f;
                }
                sa[t16][reg] = v;
            }
        }
        // ---- online softmax (row stats across l16) ----
        float mx[4];
#pragma unroll
        for (int reg = 0; reg < 4; reg++)
            mx[reg] = fmaxf(fmaxf(sa[0][reg], sa[1][reg]), fmaxf(sa[2][reg], sa[3][reg]));
#pragma unroll
        for (int off = 8; off >= 1; off >>= 1)
#pragma unroll
            for (int reg = 0; reg < 4; reg++)
                mx[reg] = fmaxf(mx[reg], __shfl_xor(mx[reg], off));
        float alpha[4];
#pragma unroll
        for (int reg = 0; reg < 4; reg++) {
            float mn = fmaxf(m[reg], mx[reg]);
            alpha[reg] = __expf(m[reg] - mn);   // m=-inf -> 0
            m[reg] = mn;
        }
        float rsum[4] = {0.f, 0.f, 0.f, 0.f};
#pragma unroll
        for (int t16 = 0; t16 < 4; t16++) {
#pragma unroll
            for (int reg = 0; reg < 4; reg++) {
                float p = __expf(sa[t16][reg] - m[reg]);
                rsum[reg] += p;
                Pl[wave][(quad * 4 + reg) * 72 + t16 * 16 + l16] = f2bfraw(p);
            }
        }
#pragma unroll
        for (int off = 8; off >= 1; off >>= 1)
#pragma unroll
            for (int reg = 0; reg < 4; reg++)
                rsum[reg] += __shfl_xor(rsum[reg], off);
#pragma unroll
        for (int reg = 0; reg < 4; reg++)
            l[reg] = l[reg] * alpha[reg] + rsum[reg];
#pragma unroll
        for (int t = 0; t < 4; t++)
#pragma unroll
            for (int reg = 0; reg < 4; reg++)
                o[t][reg] *= alpha[reg];

        __syncthreads();   // P visible (and Vt staging complete on all waves)

        // ---- O += P V ----
#pragma unroll
        for (int chunk = 0; chunk < 2; chunk++) {
            bf16x8 pf = *(const bf16x8*)&Pl[wave][l16 * 72 + chunk * 32 + quad * 8];
#pragma unroll
            for (int dt = 0; dt < 4; dt++) {
                bf16x8 vf = *(const bf16x8*)&Vt[(dt * 16 + l16) * 72 + chunk * 32 + quad * 8];
                o[dt] = __builtin_amdgcn_mfma_f32_16x16x32_bf16(pf, vf, o[dt], 0, 0, 0);
            }
        }
    }

    // ---- write O/l into dead Q slot ----
#pragma unroll
    for (int dt = 0; dt < 4; dt++) {
#pragma unroll
        for (int reg = 0; reg < 4; reg++) {
            int r = qbase + quad * 4 + reg;
            float v = o[dt][reg] / l[reg];
            base[(size_t)r * rs + h * D_ + dt * 16 + l16] = __float2bfloat16(v);
        }
    }
}

extern "C" void kernel_launch(void* const* d_in, const int* in_sizes, int n_in,
                              void* d_out, int out_size, void* d_ws, size_t ws_size,
                              hipStream_t stream)
{
    const float* x     = (const float*)d_in[0];
    const float* ln1_g = (const float*)d_in[1];
    const float* ln1_b = (const float*)d_in[2];
    const float* qkv_w = (const float*)d_in[3];
    const float* qkv_b = (const float*)d_in[4];
    const float* out_w = (const float*)d_in[5];
    const float* out_b = (const float*)d_in[6];
    const float* ln2_g = (const float*)d_in[7];
    const float* ln2_b = (const float*)d_in[8];
    const float* ff1_w = (const float*)d_in[9];
    const float* ff1_b = (const float*)d_in[10];
    const float* ff2_w = (const float*)d_in[11];
    const float* ff2_b = (const float*)d_in[12];

    // ws: [0,24M) qkv bf16 [4096,3072] (Q: q->attnout->ff1act, K: k->ff1act,
    //     V: v->x1 residual); [24M,+32K) stats1; [+32K,+32K) stats2
    char* ws = (char*)d_ws;
    __hip_bfloat16* qkv = (__hip_bfloat16*)ws;
    float2* S1 = (float2*)(ws + 25165824);
    float2* S2 = (float2*)(ws + 25165824 + 32768);
    __hip_bfloat16* x1  = qkv + 2048;               // V slots, ld = 3072

    stats_kernel<1><<<BT_, 256, 0, stream>>>(x, C_, S1);
    {
        dim3 g(3 * C_ / 64, BT_ / 64);
        gemm_mfma<1,1,0,0,0><<<g, 256, 0, stream>>>(
            x, C_, S1, ln1_g, ln1_b, qkv_w, 3 * C_, 0, qkv_b, 0,
            nullptr, 0, qkv, 3 * C_, 3 * C_, C_);
    }
    {
        dim3 g(T_ / 64, H_, B_);
        attn_flash<<<g, 256, 0, stream>>>(qkv);
    }
    {
        dim3 g(C_ / 64, BT_ / 64);
        gemm_mfma<0,0,0,1,0><<<g, 256, 0, stream>>>(
            qkv, 3 * C_, nullptr, nullptr, nullptr, out_w, C_, 0, out_b, 0,
            x, C_, x1, 3 * C_, C_, C_);
    }
    stats_kernel<0><<<BT_, 256, 0, stream>>>(x1, 3 * C_, S2);
    for (int f = 0; f < 2; f++) {
        {
            dim3 g(2048 / 64, BT_ / 64);
            gemm_mfma<1,0,1,0,0><<<g, 256, 0, stream>>>(
                x1, 3 * C_, S2, ln2_g, ln2_b, ff1_w, F_, (size_t)f * 2048, ff1_b, f * 2048,
                nullptr, 0, qkv, 3 * C_, 2048, C_);
        }
        {
            dim3 g(C_ / 64, BT_ / 64);
            if (f == 0)
                gemm_mfma<0,0,0,2,1><<<g, 256, 0, stream>>>(
                    qkv, 3 * C_, nullptr, nullptr, nullptr, ff2_w, C_, 0,
                    ff2_b, 0, x1, 3 * C_, d_out, C_, C_, 2048);
            else
                gemm_mfma<0,0,0,3,1><<<g, 256, 0, stream>>>(
                    qkv, 3 * C_, nullptr, nullptr, nullptr, ff2_w, C_, (size_t)2048 * C_,
                    nullptr, 0, d_out, C_, d_out, C_, C_, 2048);
        }
    }
}

// Round 8
// 668.625 us; speedup vs baseline: 8.0445x; 1.3505x over previous
//
#include <hip/hip_runtime.h>
#include <hip/hip_bf16.h>
#include <math.h>

#define B_ 2
#define T_ 2048
#define C_ 1024
#define H_ 16
#define D_ 64
#define F_ 4096
#define BT_ (B_*T_)

typedef __attribute__((ext_vector_type(8))) short bf16x8;
typedef __attribute__((ext_vector_type(4))) float f32x4;

__device__ __forceinline__ float bfraw2f(unsigned int u){
    union { unsigned int i; float f; } c; c.i = u << 16; return c.f;
}
// f32 -> bf16 raw bits, round-to-nearest-even
__device__ __forceinline__ short f2bfraw(float f){
    union { float f; unsigned int i; } c; c.f = f;
    unsigned int u = c.i;
    u += 0x7fffu + ((u >> 16) & 1u);
    return (short)(u >> 16);
}
// async global->LDS, 16B per lane; LDS dest = wave-uniform base + lane*16
__device__ __forceinline__ void gl2lds16(const void* g, void* l) {
    __builtin_amdgcn_global_load_lds(
        (const __attribute__((address_space(1))) unsigned int*)g,
        (__attribute__((address_space(3))) unsigned int*)l,
        16, 0, 0);
}

// ---------------- weight convert + transpose: W[K][N] f32 -> Wt[N][K] bf16 ----
__global__ __launch_bounds__(256) void wconv_t(const float* __restrict__ W,
                                               short* __restrict__ Wt,
                                               int K, int N)
{
    __shared__ short tile[64][65];
    int k0 = blockIdx.y * 64, n0 = blockIdx.x * 64;
    int t = threadIdx.x;
#pragma unroll
    for (int i = 0; i < 4; i++) {
        int idx = t + i * 256;               // float4 units over 64x64
        int r = idx >> 4, c4 = (idx & 15) * 4;
        float4 u = *(const float4*)(W + (size_t)(k0 + r) * N + n0 + c4);
        tile[c4 + 0][r] = f2bfraw(u.x);
        tile[c4 + 1][r] = f2bfraw(u.y);
        tile[c4 + 2][r] = f2bfraw(u.z);
        tile[c4 + 3][r] = f2bfraw(u.w);
    }
    __syncthreads();
#pragma unroll
    for (int i = 0; i < 2; i++) {
        int idx = t + i * 256;               // short8 units over 64x64
        int r = idx >> 3, c8 = (idx & 7) * 8;
        short v[8];
#pragma unroll
        for (int u8 = 0; u8 < 8; u8++) v[u8] = tile[r][c8 + u8];
        *(uint4*)(Wt + (size_t)(n0 + r) * K + k0 + c8) = *(const uint4*)v;
    }
}

// ---------------- per-row LN stats ----------------
template<int XF>
__global__ __launch_bounds__(256) void stats_kernel(const void* __restrict__ x, int ld,
                                                    float2* __restrict__ out)
{
    __shared__ float sm1[4], sm2[4];
    int row = blockIdx.x;
    size_t base = (size_t)row * ld;
    int t = threadIdx.x;
    float s = 0.f, ss = 0.f;
#pragma unroll
    for (int i = 0; i < 4; i++) {
        float f = XF ? ((const float*)x)[base + i*256 + t]
                     : (float)((const __hip_bfloat16*)x)[base + i*256 + t];
        s += f; ss += f * f;
    }
#pragma unroll
    for (int off = 32; off >= 1; off >>= 1) {
        s  += __shfl_xor(s,  off);
        ss += __shfl_xor(ss, off);
    }
    int wave = t >> 6, lane = t & 63;
    if (!lane) { sm1[wave] = s; sm2[wave] = ss; }
    __syncthreads();
    if (t == 0) {
        s  = sm1[0] + sm1[1] + sm1[2] + sm1[3];
        ss = sm2[0] + sm2[1] + sm2[2] + sm2[3];
        float mu  = s * (1.f / C_);
        float var = ss * (1.f / C_) - mu * mu;
        if (var < 0.f) var = 0.f;
        out[row] = make_float2(mu, rsqrtf(var + 1e-5f));
    }
}

// ---------------- LN apply -> bf16 out[row*ldo + c] ----------------
template<int XF>
__global__ __launch_bounds__(256) void ln_apply(const void* __restrict__ x, int ld,
                                                const float2* __restrict__ stats,
                                                const float* __restrict__ g,
                                                const float* __restrict__ b,
                                                __hip_bfloat16* out, int ldo)
{
    int row = blockIdx.x, t = threadIdx.x;
    float2 st = stats[row];
#pragma unroll
    for (int i = 0; i < 4; i++) {
        int c = t + i * 256;
        float f = XF ? ((const float*)x)[(size_t)row * ld + c]
                     : (float)((const __hip_bfloat16*)x)[(size_t)row * ld + c];
        out[(size_t)row * ldo + c] = __float2bfloat16((f - st.x) * st.y * g[c] + b[c]);
    }
}

// ---------------- 128x128 MFMA GEMM (m97 structure) ----------------
// out[M,N] = A[M,K](bf16) @ Wt[N,K]^T(bf16) + bias (+GELU)(+res)
// ACT: 1 exact GELU. RES: 0 none, 1 fp32, 2 bf16 (ld), 3 fp32 in-place d_out.
// OUTF: 0 bf16, 1 fp32. 4 waves; wave w=(wm,wn) computes 64x64 quadrant.
template<int ACT, int RES, int OUTF>
__global__ __launch_bounds__(256) void gemm128(
    const __hip_bfloat16* A, int lda,
    const short* Wt, int ldw, int noff, int koff,
    const float* __restrict__ bias, int boff,
    const void* res, int ldres,
    void* out, int ldo,
    int K)
{
    __shared__ __align__(16) short As[128 * 32];   // [m][k] unpadded (global_load_lds)
    __shared__ __align__(16) short Bs[128 * 32];   // [n][k] unpadded
    int tid = threadIdx.x;
    int w = tid >> 6, lane = tid & 63;
    int quad = lane >> 4, l16 = lane & 15;
    int wm = w >> 1, wn = w & 1;
    int m0 = blockIdx.y * 128, n0 = blockIdx.x * 128;
    int lr = lane >> 2, lk = (lane & 3) * 8;       // 4 lanes per row, 8 bf16 each

    const __hip_bfloat16* Ag = A + (size_t)(m0 + w * 32 + lr) * lda + lk;
    const short*          Bg = Wt + (size_t)(noff + n0 + w * 32 + lr) * ldw + koff + lk;
    short* Al0 = &As[(w * 32) * 32];
    short* Al1 = &As[(w * 32 + 16) * 32];
    short* Bl0 = &Bs[(w * 32) * 32];
    short* Bl1 = &Bs[(w * 32 + 16) * 32];

    f32x4 acc[4][4];
#pragma unroll
    for (int i = 0; i < 4; i++)
#pragma unroll
        for (int j = 0; j < 4; j++) acc[i][j] = (f32x4){0.f, 0.f, 0.f, 0.f};

    for (int k0 = 0; k0 < K; k0 += 32) {
        gl2lds16(Ag + k0,            Al0);
        gl2lds16(Ag + 16 * lda + k0, Al1);
        gl2lds16(Bg + k0,            Bl0);
        gl2lds16(Bg + 16 * ldw + k0, Bl1);
        __syncthreads();
        bf16x8 af[4], bfr[4];
#pragma unroll
        for (int mt = 0; mt < 4; mt++)
            af[mt] = *(const bf16x8*)&As[(wm * 64 + mt * 16 + l16) * 32 + quad * 8];
#pragma unroll
        for (int nt = 0; nt < 4; nt++)
            bfr[nt] = *(const bf16x8*)&Bs[(wn * 64 + nt * 16 + l16) * 32 + quad * 8];
#pragma unroll
        for (int mt = 0; mt < 4; mt++)
#pragma unroll
            for (int nt = 0; nt < 4; nt++)
                acc[mt][nt] = __builtin_amdgcn_mfma_f32_16x16x32_bf16(af[mt], bfr[nt], acc[mt][nt], 0, 0, 0);
        __syncthreads();
    }

    // epilogue: C col = l16 (+n tile), row = quad*4 + reg (+m tile)
#pragma unroll
    for (int nt = 0; nt < 4; nt++) {
        int c = n0 + wn * 64 + nt * 16 + l16;
        float bv = bias ? bias[boff + c] : 0.f;
#pragma unroll
        for (int mt = 0; mt < 4; mt++) {
#pragma unroll
            for (int reg = 0; reg < 4; reg++) {
                int r = m0 + wm * 64 + mt * 16 + quad * 4 + reg;
                float v = acc[mt][nt][reg] + bv;
                if (ACT == 1) v = 0.5f * v * (1.f + erff(v * 0.70710678118654752f));
                if (RES == 1) v += ((const float*)res)[(size_t)r * ldres + c];
                if (RES == 2) v += (float)((const __hip_bfloat16*)res)[(size_t)r * ldres + c];
                if (RES == 3) v += ((const float*)res)[(size_t)r * ldres + c];
                if (OUTF) ((float*)out)[(size_t)r * ldo + c] = v;
                else ((__hip_bfloat16*)out)[(size_t)r * ldo + c] = __float2bfloat16(v);
            }
        }
    }
}

// ---------------- MFMA flash attention (unchanged from R6 — passed) ----------
__global__ __launch_bounds__(256) void attn_flash(__hip_bfloat16* qkv)
{
    __shared__ __align__(16) short Vt[64 * 72];
    __shared__ __align__(16) short Pl[4][16 * 72];
    int tid = threadIdx.x;
    int wave = tid >> 6, lane = tid & 63;
    int quad = lane >> 4, l16 = lane & 15;
    int qb = (gridDim.x - 1) - blockIdx.x;
    int h = blockIdx.y, b = blockIdx.z;
    const size_t rs = 3 * C_;
    __hip_bfloat16* base = qkv + (size_t)b * T_ * rs;
    const __hip_bfloat16* Qb = base + h * D_;
    const __hip_bfloat16* Kb = base + C_ + h * D_;
    const __hip_bfloat16* Vb = base + 2 * C_ + h * D_;
    int qbase = qb * 64 + wave * 16;

    bf16x8 qf0 = *(const bf16x8*)(Qb + (size_t)(qbase + l16) * rs + quad * 8);
    bf16x8 qf1 = *(const bf16x8*)(Qb + (size_t)(qbase + l16) * rs + 32 + quad * 8);

    f32x4 o[4];
#pragma unroll
    for (int t = 0; t < 4; t++) o[t] = (f32x4){0.f, 0.f, 0.f, 0.f};
    float m[4] = {-INFINITY, -INFINITY, -INFINITY, -INFINITY};
    float l[4] = {0.f, 0.f, 0.f, 0.f};

    int vkey = tid & 63, vg0 = tid >> 6;

    for (int kt = 0; kt <= qb; kt++) {
        int kb = kt * 64;
        __syncthreads();
#pragma unroll
        for (int it = 0; it < 2; it++) {
            int d0 = (vg0 + it * 4) * 8;
            uint4 u = *(const uint4*)(Vb + (size_t)(kb + vkey) * rs + d0);
            union { uint4 v; short s[8]; } cc; cc.v = u;
#pragma unroll
            for (int u8 = 0; u8 < 8; u8++)
                Vt[(d0 + u8) * 72 + vkey] = cc.s[u8];
        }
        __syncthreads();

        f32x4 sa[4];
#pragma unroll
        for (int t16 = 0; t16 < 4; t16++) {
            const __hip_bfloat16* kr = Kb + (size_t)(kb + t16 * 16 + l16) * rs;
            bf16x8 kf0 = *(const bf16x8*)(kr + quad * 8);
            bf16x8 kf1 = *(const bf16x8*)(kr + 32 + quad * 8);
            f32x4 s = (f32x4){0.f, 0.f, 0.f, 0.f};
            s = __builtin_amdgcn_mfma_f32_16x16x32_bf16(qf0, kf0, s, 0, 0, 0);
            s = __builtin_amdgcn_mfma_f32_16x16x32_bf16(qf1, kf1, s, 0, 0, 0);
            sa[t16] = s;
        }
#pragma unroll
        for (int t16 = 0; t16 < 4; t16++) {
#pragma unroll
            for (int reg = 0; reg < 4; reg++) {
                float v = sa[t16][reg] * 0.125f;
                if (kt == qb) {
                    int keyl = t16 * 16 + l16;
                    int ql = wave * 16 + quad * 4 + reg;
                    if (keyl > ql) v = -3.0e38f;
                }
                sa[t16][reg] = v;
            }
        }
        float mx[4];
#pragma unroll
        for (int reg = 0; reg < 4; reg++)
            mx[reg] = fmaxf(fmaxf(sa[0][reg], sa[1][reg]), fmaxf(sa[2][reg], sa[3][reg]));
#pragma unroll
        for (int off = 8; off >= 1; off >>= 1)
#pragma unroll
            for (int reg = 0; reg < 4; reg++)
                mx[reg] = fmaxf(mx[reg], __shfl_xor(mx[reg], off));
        float alpha[4];
#pragma unroll
        for (int reg = 0; reg < 4; reg++) {
            float mn = fmaxf(m[reg], mx[reg]);
            alpha[reg] = __expf(m[reg] - mn);
            m[reg] = mn;
        }
        float rsum[4] = {0.f, 0.f, 0.f, 0.f};
#pragma unroll
        for (int t16 = 0; t16 < 4; t16++) {
#pragma unroll
            for (int reg = 0; reg < 4; reg++) {
                float p = __expf(sa[t16][reg] - m[reg]);
                rsum[reg] += p;
                Pl[wave][(quad * 4 + reg) * 72 + t16 * 16 + l16] = f2bfraw(p);
            }
        }
#pragma unroll
        for (int off = 8; off >= 1; off >>= 1)
#pragma unroll
            for (int reg = 0; reg < 4; reg++)
                rsum[reg] += __shfl_xor(rsum[reg], off);
#pragma unroll
        for (int reg = 0; reg < 4; reg++)
            l[reg] = l[reg] * alpha[reg] + rsum[reg];
#pragma unroll
        for (int t = 0; t < 4; t++)
#pragma unroll
            for (int reg = 0; reg < 4; reg++)
                o[t][reg] *= alpha[reg];

        __syncthreads();

#pragma unroll
        for (int chunk = 0; chunk < 2; chunk++) {
            bf16x8 pf = *(const bf16x8*)&Pl[wave][l16 * 72 + chunk * 32 + quad * 8];
#pragma unroll
            for (int dt = 0; dt < 4; dt++) {
                bf16x8 vf = *(const bf16x8*)&Vt[(dt * 16 + l16) * 72 + chunk * 32 + quad * 8];
                o[dt] = __builtin_amdgcn_mfma_f32_16x16x32_bf16(pf, vf, o[dt], 0, 0, 0);
            }
        }
    }

#pragma unroll
    for (int dt = 0; dt < 4; dt++) {
#pragma unroll
        for (int reg = 0; reg < 4; reg++) {
            int r = qbase + quad * 4 + reg;
            float v = o[dt][reg] / l[reg];
            base[(size_t)r * rs + h * D_ + dt * 16 + l16] = __float2bfloat16(v);
        }
    }
}

extern "C" void kernel_launch(void* const* d_in, const int* in_sizes, int n_in,
                              void* d_out, int out_size, void* d_ws, size_t ws_size,
                              hipStream_t stream)
{
    const float* x     = (const float*)d_in[0];
    const float* ln1_g = (const float*)d_in[1];
    const float* ln1_b = (const float*)d_in[2];
    const float* qkv_w = (const float*)d_in[3];
    const float* qkv_b = (const float*)d_in[4];
    const float* out_w = (const float*)d_in[5];
    const float* out_b = (const float*)d_in[6];
    const float* ln2_g = (const float*)d_in[7];
    const float* ln2_b = (const float*)d_in[8];
    const float* ff1_w = (const float*)d_in[9];
    const float* ff1_b = (const float*)d_in[10];
    const float* ff2_w = (const float*)d_in[11];
    const float* ff2_b = (const float*)d_in[12];

    // ws (48 MiB): [0,24M) qkv bf16 [4096][3072]
    //   Q cols 0..1023: q -> attn-out -> hbuf2 (LN2 out, live whole FF phase)
    //   K cols 1024..2047: k -> ff1 act chunk (width 1024, rewritten per chunk)
    //   V cols 2048..3071: v -> x1 residual (dead after FF2 f==0)
    //   [24M,30M) qkvW^T; [30M,32M) outW^T; [32M,40M) ff1W^T; [40M,48M) ff2W^T
    // d_out (16 MiB) scratch until FF2 writes it:
    //   [0,8M) hbuf1 (LN1 out, dead after QKV GEMM)
    //   [8M,+32K) S1 (dead after ln_apply<1>); [+32K,+32K) S2 (dead after ln_apply<0>)
    char* ws = (char*)d_ws;
    __hip_bfloat16* qkv = (__hip_bfloat16*)ws;
    short* qkvwT = (short*)(ws + 25165824);
    short* outwT = (short*)(ws + 31457280);
    short* ff1wT = (short*)(ws + 33554432);
    short* ff2wT = (short*)(ws + 41943040);
    __hip_bfloat16* hbuf2 = qkv;                           // Q slots, ld 3072
    __hip_bfloat16* act   = qkv + 1024;                    // K slots, ld 3072
    __hip_bfloat16* x1    = qkv + 2048;                    // V slots, ld 3072
    char* db = (char*)d_out;
    __hip_bfloat16* hbuf1 = (__hip_bfloat16*)db;           // ld 1024
    float2* S1 = (float2*)(db + 8388608);
    float2* S2 = (float2*)(db + 8388608 + 32768);

    // 0) weight convert+transpose (fp32 -> bf16 W^T)
    wconv_t<<<dim3(3 * C_ / 64, C_ / 64), 256, 0, stream>>>(qkv_w, qkvwT, C_, 3 * C_);
    wconv_t<<<dim3(C_ / 64, C_ / 64),     256, 0, stream>>>(out_w, outwT, C_, C_);
    wconv_t<<<dim3(F_ / 64, C_ / 64),     256, 0, stream>>>(ff1_w, ff1wT, C_, F_);
    wconv_t<<<dim3(C_ / 64, F_ / 64),     256, 0, stream>>>(ff2_w, ff2wT, F_, C_);

    // 1) LN1 -> hbuf1 (d_out scratch)
    stats_kernel<1><<<BT_, 256, 0, stream>>>(x, C_, S1);
    ln_apply<1><<<BT_, 256, 0, stream>>>(x, C_, S1, ln1_g, ln1_b, hbuf1, C_);
    // 2) QKV: hbuf1 @ qkv_w + qkv_b -> qkv   (hbuf1 dead after this)
    gemm128<0,0,0><<<dim3(3 * C_ / 128, BT_ / 128), 256, 0, stream>>>(
        hbuf1, C_, qkvwT, C_, 0, 0, qkv_b, 0, nullptr, 0, qkv, 3 * C_, C_);
    // 3) attention -> Q slots
    attn_flash<<<dim3(T_ / 64, H_, B_), 256, 0, stream>>>(qkv);
    // 4) out proj + residual(x fp32) -> x1 (V slots)   (Q slots dead after this)
    gemm128<0,1,0><<<dim3(C_ / 128, BT_ / 128), 256, 0, stream>>>(
        qkv, 3 * C_, outwT, C_, 0, 0, out_b, 0, x, C_, x1, 3 * C_, C_);
    // 5) LN2 -> hbuf2 (Q slots)
    stats_kernel<0><<<BT_, 256, 0, stream>>>(x1, 3 * C_, S2);
    ln_apply<0><<<BT_, 256, 0, stream>>>(x1, 3 * C_, S2, ln2_g, ln2_b, hbuf2, 3 * C_);
    // 6) FF in four 1024-wide chunks: act -> K slots, accumulate into d_out fp32
    for (int f = 0; f < 4; f++) {
        gemm128<1,0,0><<<dim3(1024 / 128, BT_ / 128), 256, 0, stream>>>(
            hbuf2, 3 * C_, ff1wT, C_, f * 1024, 0, ff1_b, f * 1024,
            nullptr, 0, act, 3 * C_, C_);
        if (f == 0)
            gemm128<0,2,1><<<dim3(C_ / 128, BT_ / 128), 256, 0, stream>>>(
                act, 3 * C_, ff2wT, F_, 0, 0, ff2_b, 0,
                x1, 3 * C_, d_out, C_, 1024);
        else
            gemm128<0,3,1><<<dim3(C_ / 128, BT_ / 128), 256, 0, stream>>>(
                act, 3 * C_, ff2wT, F_, 0, f * 1024, nullptr, 0,
                d_out, C_, d_out, C_, 1024);
    }
}

// Round 10
// 531.709 us; speedup vs baseline: 10.1160x; 1.2575x over previous
//
#include <hip/hip_runtime.h>
#include <hip/hip_bf16.h>
#include <math.h>

#define B_ 2
#define T_ 2048
#define C_ 1024
#define H_ 16
#define D_ 64
#define F_ 4096
#define BT_ (B_*T_)

typedef __attribute__((ext_vector_type(8))) short bf16x8;
typedef __attribute__((ext_vector_type(4))) float f32x4;

__device__ __forceinline__ float bfraw2f(unsigned int u){
    union { unsigned int i; float f; } c; c.i = u << 16; return c.f;
}
// f32 -> bf16 raw bits, round-to-nearest-even
__device__ __forceinline__ short f2bfraw(float f){
    union { float f; unsigned int i; } c; c.f = f;
    unsigned int u = c.i;
    u += 0x7fffu + ((u >> 16) & 1u);
    return (short)(u >> 16);
}
// async global->LDS, 16B per lane; LDS dest = wave-uniform base + lane*16
__device__ __forceinline__ void gl2lds16(const void* g, void* l) {
    __builtin_amdgcn_global_load_lds(
        (const __attribute__((address_space(1))) unsigned int*)g,
        (__attribute__((address_space(3))) unsigned int*)l,
        16, 0, 0);
}

// ---------------- weight convert + transpose: W[K][N] f32 -> Wt[N][K] bf16 ----
__global__ __launch_bounds__(256) void wconv_t(const float* __restrict__ W,
                                               short* __restrict__ Wt,
                                               int K, int N)
{
    __shared__ short tile[64][65];
    int k0 = blockIdx.y * 64, n0 = blockIdx.x * 64;
    int t = threadIdx.x;
#pragma unroll
    for (int i = 0; i < 4; i++) {
        int idx = t + i * 256;
        int r = idx >> 4, c4 = (idx & 15) * 4;
        float4 u = *(const float4*)(W + (size_t)(k0 + r) * N + n0 + c4);
        tile[c4 + 0][r] = f2bfraw(u.x);
        tile[c4 + 1][r] = f2bfraw(u.y);
        tile[c4 + 2][r] = f2bfraw(u.z);
        tile[c4 + 3][r] = f2bfraw(u.w);
    }
    __syncthreads();
#pragma unroll
    for (int i = 0; i < 2; i++) {
        int idx = t + i * 256;
        int r = idx >> 3, c8 = (idx & 7) * 8;
        short v[8];
#pragma unroll
        for (int u8 = 0; u8 < 8; u8++) v[u8] = tile[r][c8 + u8];
        *(uint4*)(Wt + (size_t)(n0 + r) * K + k0 + c8) = *(const uint4*)v;
    }
}

// ---------------- fused LayerNorm (fp32 in, bf16 out) ----------------
__global__ __launch_bounds__(256) void ln_fused(const float* __restrict__ x, int ldx,
                                                const float* __restrict__ g,
                                                const float* __restrict__ b,
                                                __hip_bfloat16* out, int ldo)
{
    __shared__ float sm1[4], sm2[4];
    __shared__ float smu, srs;
    int row = blockIdx.x, t = threadIdx.x;
    const float* xr = x + (size_t)row * ldx;
    float v[4]; float s = 0.f, ss = 0.f;
#pragma unroll
    for (int i = 0; i < 4; i++) {
        float f = xr[t + i * 256];
        v[i] = f; s += f; ss += f * f;
    }
#pragma unroll
    for (int off = 32; off >= 1; off >>= 1) {
        s  += __shfl_xor(s,  off);
        ss += __shfl_xor(ss, off);
    }
    int wave = t >> 6, lane = t & 63;
    if (!lane) { sm1[wave] = s; sm2[wave] = ss; }
    __syncthreads();
    if (t == 0) {
        s  = sm1[0] + sm1[1] + sm1[2] + sm1[3];
        ss = sm2[0] + sm2[1] + sm2[2] + sm2[3];
        float mu  = s * (1.f / C_);
        float var = ss * (1.f / C_) - mu * mu;
        if (var < 0.f) var = 0.f;
        smu = mu; srs = rsqrtf(var + 1e-5f);
    }
    __syncthreads();
    float mu = smu, rs = srs;
#pragma unroll
    for (int i = 0; i < 4; i++) {
        int c = t + i * 256;
        out[(size_t)row * ldo + c] = __float2bfloat16((v[i] - mu) * rs * g[c] + b[c]);
    }
}

// ---------------- 128x128 MFMA GEMM ----------------
// out = A[M,K](bf16) @ Wt[N,K]^T + bias (+GELU). Out bf16.
// koff applies to Wt ONLY; A reads k from 0.
template<int ACT>
__global__ __launch_bounds__(256) void gemm128(
    const __hip_bfloat16* A, int lda,
    const short* Wt, int ldw, int noff, int koff,
    const float* __restrict__ bias, int boff,
    void* out, int ldo,
    int K)
{
    __shared__ __align__(16) short As[128 * 32];
    __shared__ __align__(16) short Bs[128 * 32];
    int tid = threadIdx.x;
    int w = tid >> 6, lane = tid & 63;
    int quad = lane >> 4, l16 = lane & 15;
    int wm = w >> 1, wn = w & 1;
    int m0 = blockIdx.y * 128, n0 = blockIdx.x * 128;
    int lr = lane >> 2, lk = (lane & 3) * 8;

    const __hip_bfloat16* Ag = A + (size_t)(m0 + w * 32 + lr) * lda + lk;
    const short*          Bg = Wt + (size_t)(noff + n0 + w * 32 + lr) * ldw + koff + lk;
    short* Al0 = &As[(w * 32) * 32];
    short* Al1 = &As[(w * 32 + 16) * 32];
    short* Bl0 = &Bs[(w * 32) * 32];
    short* Bl1 = &Bs[(w * 32 + 16) * 32];

    f32x4 acc[4][4];
#pragma unroll
    for (int i = 0; i < 4; i++)
#pragma unroll
        for (int j = 0; j < 4; j++) acc[i][j] = (f32x4){0.f, 0.f, 0.f, 0.f};

    for (int k0 = 0; k0 < K; k0 += 32) {
        gl2lds16(Ag + k0,            Al0);
        gl2lds16(Ag + 16 * lda + k0, Al1);
        gl2lds16(Bg + k0,            Bl0);
        gl2lds16(Bg + 16 * ldw + k0, Bl1);
        __syncthreads();
        bf16x8 af[4], bfr[4];
#pragma unroll
        for (int mt = 0; mt < 4; mt++)
            af[mt] = *(const bf16x8*)&As[(wm * 64 + mt * 16 + l16) * 32 + quad * 8];
#pragma unroll
        for (int nt = 0; nt < 4; nt++)
            bfr[nt] = *(const bf16x8*)&Bs[(wn * 64 + nt * 16 + l16) * 32 + quad * 8];
#pragma unroll
        for (int mt = 0; mt < 4; mt++)
#pragma unroll
            for (int nt = 0; nt < 4; nt++)
                acc[mt][nt] = __builtin_amdgcn_mfma_f32_16x16x32_bf16(af[mt], bfr[nt], acc[mt][nt], 0, 0, 0);
        __syncthreads();
    }

#pragma unroll
    for (int nt = 0; nt < 4; nt++) {
        int c = n0 + wn * 64 + nt * 16 + l16;
        float bv = bias ? bias[boff + c] : 0.f;
#pragma unroll
        for (int mt = 0; mt < 4; mt++) {
#pragma unroll
            for (int reg = 0; reg < 4; reg++) {
                int r = m0 + wm * 64 + mt * 16 + quad * 4 + reg;
                float v = acc[mt][nt][reg] + bv;
                if (ACT == 1) v = 0.5f * v * (1.f + erff(v * 0.70710678118654752f));
                ((__hip_bfloat16*)out)[(size_t)r * ldo + c] = __float2bfloat16(v);
            }
        }
    }
}

// ---------------- 64x128 MFMA GEMM, fp32 out with fp32 residual add ----------
// out[r][c] = A@Wt^T + (bias?) + res[r][c]   (res may alias out: in-place RMW)
// koff applies to Wt ONLY; A reads k from 0.   <-- R9 bug fix
__global__ __launch_bounds__(256) void gemm64(
    const __hip_bfloat16* A, int lda,
    const short* Wt, int ldw, int koff,
    const float* __restrict__ bias,
    const float* res, int ldres,
    float* out, int ldo,
    int K)
{
    __shared__ __align__(16) short As[64 * 32];    // [m][k]
    __shared__ __align__(16) short Bs[128 * 32];   // [n][k]
    int tid = threadIdx.x;
    int w = tid >> 6, lane = tid & 63;
    int quad = lane >> 4, l16 = lane & 15;
    int m0 = blockIdx.y * 64, n0 = blockIdx.x * 128;
    int lr = lane >> 2, lk = (lane & 3) * 8;

    const __hip_bfloat16* Ag = A + (size_t)(m0 + w * 16 + lr) * lda + lk;          // no koff
    const short*          Bg = Wt + (size_t)(n0 + w * 32 + lr) * ldw + koff + lk;  // koff here only
    short* Al  = &As[(w * 16) * 32];
    short* Bl0 = &Bs[(w * 32) * 32];
    short* Bl1 = &Bs[(w * 32 + 16) * 32];

    f32x4 acc[8];
#pragma unroll
    for (int j = 0; j < 8; j++) acc[j] = (f32x4){0.f, 0.f, 0.f, 0.f};

    for (int k0 = 0; k0 < K; k0 += 32) {
        gl2lds16(Ag + k0,            Al);
        gl2lds16(Bg + k0,            Bl0);
        gl2lds16(Bg + 16 * ldw + k0, Bl1);
        __syncthreads();
        bf16x8 af = *(const bf16x8*)&As[(w * 16 + l16) * 32 + quad * 8];
#pragma unroll
        for (int nt = 0; nt < 8; nt++) {
            bf16x8 bfr = *(const bf16x8*)&Bs[(nt * 16 + l16) * 32 + quad * 8];
            acc[nt] = __builtin_amdgcn_mfma_f32_16x16x32_bf16(af, bfr, acc[nt], 0, 0, 0);
        }
        __syncthreads();
    }

#pragma unroll
    for (int nt = 0; nt < 8; nt++) {
        int c = n0 + nt * 16 + l16;
        float bv = bias ? bias[c] : 0.f;
#pragma unroll
        for (int reg = 0; reg < 4; reg++) {
            int r = m0 + w * 16 + quad * 4 + reg;
            float v = acc[nt][reg] + bv + res[(size_t)r * ldres + c];
            out[(size_t)r * ldo + c] = v;
        }
    }
}

// ---------------- MFMA flash attention (unchanged — passed R6/R8) ----------
__global__ __launch_bounds__(256) void attn_flash(__hip_bfloat16* qkv)
{
    __shared__ __align__(16) short Vt[64 * 72];
    __shared__ __align__(16) short Pl[4][16 * 72];
    int tid = threadIdx.x;
    int wave = tid >> 6, lane = tid & 63;
    int quad = lane >> 4, l16 = lane & 15;
    int qb = (gridDim.x - 1) - blockIdx.x;
    int h = blockIdx.y, b = blockIdx.z;
    const size_t rs = 3 * C_;
    __hip_bfloat16* base = qkv + (size_t)b * T_ * rs;
    const __hip_bfloat16* Qb = base + h * D_;
    const __hip_bfloat16* Kb = base + C_ + h * D_;
    const __hip_bfloat16* Vb = base + 2 * C_ + h * D_;
    int qbase = qb * 64 + wave * 16;

    bf16x8 qf0 = *(const bf16x8*)(Qb + (size_t)(qbase + l16) * rs + quad * 8);
    bf16x8 qf1 = *(const bf16x8*)(Qb + (size_t)(qbase + l16) * rs + 32 + quad * 8);

    f32x4 o[4];
#pragma unroll
    for (int t = 0; t < 4; t++) o[t] = (f32x4){0.f, 0.f, 0.f, 0.f};
    float m[4] = {-INFINITY, -INFINITY, -INFINITY, -INFINITY};
    float l[4] = {0.f, 0.f, 0.f, 0.f};

    int vkey = tid & 63, vg0 = tid >> 6;

    for (int kt = 0; kt <= qb; kt++) {
        int kb = kt * 64;
        __syncthreads();
#pragma unroll
        for (int it = 0; it < 2; it++) {
            int d0 = (vg0 + it * 4) * 8;
            uint4 u = *(const uint4*)(Vb + (size_t)(kb + vkey) * rs + d0);
            union { uint4 v; short s[8]; } cc; cc.v = u;
#pragma unroll
            for (int u8 = 0; u8 < 8; u8++)
                Vt[(d0 + u8) * 72 + vkey] = cc.s[u8];
        }
        __syncthreads();

        f32x4 sa[4];
#pragma unroll
        for (int t16 = 0; t16 < 4; t16++) {
            const __hip_bfloat16* kr = Kb + (size_t)(kb + t16 * 16 + l16) * rs;
            bf16x8 kf0 = *(const bf16x8*)(kr + quad * 8);
            bf16x8 kf1 = *(const bf16x8*)(kr + 32 + quad * 8);
            f32x4 s = (f32x4){0.f, 0.f, 0.f, 0.f};
            s = __builtin_amdgcn_mfma_f32_16x16x32_bf16(qf0, kf0, s, 0, 0, 0);
            s = __builtin_amdgcn_mfma_f32_16x16x32_bf16(qf1, kf1, s, 0, 0, 0);
            sa[t16] = s;
        }
#pragma unroll
        for (int t16 = 0; t16 < 4; t16++) {
#pragma unroll
            for (int reg = 0; reg < 4; reg++) {
                float v = sa[t16][reg] * 0.125f;
                if (kt == qb) {
                    int keyl = t16 * 16 + l16;
                    int ql = wave * 16 + quad * 4 + reg;
                    if (keyl > ql) v = -3.0e38f;
                }
                sa[t16][reg] = v;
            }
        }
        float mx[4];
#pragma unroll
        for (int reg = 0; reg < 4; reg++)
            mx[reg] = fmaxf(fmaxf(sa[0][reg], sa[1][reg]), fmaxf(sa[2][reg], sa[3][reg]));
#pragma unroll
        for (int off = 8; off >= 1; off >>= 1)
#pragma unroll
            for (int reg = 0; reg < 4; reg++)
                mx[reg] = fmaxf(mx[reg], __shfl_xor(mx[reg], off));
        float alpha[4];
#pragma unroll
        for (int reg = 0; reg < 4; reg++) {
            float mn = fmaxf(m[reg], mx[reg]);
            alpha[reg] = __expf(m[reg] - mn);
            m[reg] = mn;
        }
        float rsum[4] = {0.f, 0.f, 0.f, 0.f};
#pragma unroll
        for (int t16 = 0; t16 < 4; t16++) {
#pragma unroll
            for (int reg = 0; reg < 4; reg++) {
                float p = __expf(sa[t16][reg] - m[reg]);
                rsum[reg] += p;
                Pl[wave][(quad * 4 + reg) * 72 + t16 * 16 + l16] = f2bfraw(p);
            }
        }
#pragma unroll
        for (int off = 8; off >= 1; off >>= 1)
#pragma unroll
            for (int reg = 0; reg < 4; reg++)
                rsum[reg] += __shfl_xor(rsum[reg], off);
#pragma unroll
        for (int reg = 0; reg < 4; reg++)
            l[reg] = l[reg] * alpha[reg] + rsum[reg];
#pragma unroll
        for (int t = 0; t < 4; t++)
#pragma unroll
            for (int reg = 0; reg < 4; reg++)
                o[t][reg] *= alpha[reg];

        __syncthreads();

#pragma unroll
        for (int chunk = 0; chunk < 2; chunk++) {
            bf16x8 pf = *(const bf16x8*)&Pl[wave][l16 * 72 + chunk * 32 + quad * 8];
#pragma unroll
            for (int dt = 0; dt < 4; dt++) {
                bf16x8 vf = *(const bf16x8*)&Vt[(dt * 16 + l16) * 72 + chunk * 32 + quad * 8];
                o[dt] = __builtin_amdgcn_mfma_f32_16x16x32_bf16(pf, vf, o[dt], 0, 0, 0);
            }
        }
    }

#pragma unroll
    for (int dt = 0; dt < 4; dt++) {
#pragma unroll
        for (int reg = 0; reg < 4; reg++) {
            int r = qbase + quad * 4 + reg;
            float v = o[dt][reg] / l[reg];
            base[(size_t)r * rs + h * D_ + dt * 16 + l16] = __float2bfloat16(v);
        }
    }
}

extern "C" void kernel_launch(void* const* d_in, const int* in_sizes, int n_in,
                              void* d_out, int out_size, void* d_ws, size_t ws_size,
                              hipStream_t stream)
{
    const float* x     = (const float*)d_in[0];
    const float* ln1_g = (const float*)d_in[1];
    const float* ln1_b = (const float*)d_in[2];
    const float* qkv_w = (const float*)d_in[3];
    const float* qkv_b = (const float*)d_in[4];
    const float* out_w = (const float*)d_in[5];
    const float* out_b = (const float*)d_in[6];
    const float* ln2_g = (const float*)d_in[7];
    const float* ln2_b = (const float*)d_in[8];
    const float* ff1_w = (const float*)d_in[9];
    const float* ff1_b = (const float*)d_in[10];
    const float* ff2_w = (const float*)d_in[11];
    const float* ff2_b = (const float*)d_in[12];

    // ws (48 MiB): [0,24M) qkv bf16 [4096][3072]
    //   Q cols 0..1023: q -> attn-out -> hbuf2 (LN2 out, live whole FF phase)
    //   K+V cols 1024..3071: k,v -> ff1 act chunk (width 2048, per chunk)
    //   [24M,30M) qkvW^T; [30M,32M) outW^T; [32M,40M) ff1W^T; [40M,48M) ff2W^T
    // d_out (16 MiB fp32 [4096][1024]):
    //   phase 1: [0,8M) hbuf1 bf16 (LN1 out, dead after QKV GEMM)
    //   phase 2: x1 residual fp32 (out-proj), FF2 accumulates in place.
    char* ws = (char*)d_ws;
    __hip_bfloat16* qkv = (__hip_bfloat16*)ws;
    short* qkvwT = (short*)(ws + 25165824);
    short* outwT = (short*)(ws + 31457280);
    short* ff1wT = (short*)(ws + 33554432);
    short* ff2wT = (short*)(ws + 41943040);
    __hip_bfloat16* hbuf2 = qkv;                           // Q slots, ld 3072
    __hip_bfloat16* act   = qkv + 1024;                    // K+V slots, ld 3072
    __hip_bfloat16* hbuf1 = (__hip_bfloat16*)d_out;        // ld 1024 (bf16)
    float* x1 = (float*)d_out;                             // fp32, ld 1024

    // 0) weight convert+transpose (fp32 -> bf16 W^T)
    wconv_t<<<dim3(3 * C_ / 64, C_ / 64), 256, 0, stream>>>(qkv_w, qkvwT, C_, 3 * C_);
    wconv_t<<<dim3(C_ / 64, C_ / 64),     256, 0, stream>>>(out_w, outwT, C_, C_);
    wconv_t<<<dim3(F_ / 64, C_ / 64),     256, 0, stream>>>(ff1_w, ff1wT, C_, F_);
    wconv_t<<<dim3(C_ / 64, F_ / 64),     256, 0, stream>>>(ff2_w, ff2wT, F_, C_);

    // 1) LN1(x) -> hbuf1 (d_out scratch, bf16)
    ln_fused<<<BT_, 256, 0, stream>>>(x, C_, ln1_g, ln1_b, hbuf1, C_);
    // 2) QKV: hbuf1 @ qkv_w + qkv_b -> qkv (hbuf1 dead after)
    gemm128<0><<<dim3(3 * C_ / 128, BT_ / 128), 256, 0, stream>>>(
        hbuf1, C_, qkvwT, C_, 0, 0, qkv_b, 0, qkv, 3 * C_, C_);
    // 3) attention -> Q slots
    attn_flash<<<dim3(T_ / 64, H_, B_), 256, 0, stream>>>(qkv);
    // 4) out proj + residual(x) -> x1 = d_out (fp32); Q slots dead after
    gemm64<<<dim3(C_ / 128, BT_ / 64), 256, 0, stream>>>(
        qkv, 3 * C_, outwT, C_, 0, out_b, x, C_, x1, C_, C_);
    // 5) LN2(x1) -> hbuf2 (Q slots)
    ln_fused<<<BT_, 256, 0, stream>>>(x1, C_, ln2_g, ln2_b, hbuf2, 3 * C_);
    // 6) FF in two 2048-wide chunks; act in K+V slots; FF2 accumulates into
    //    d_out in place.
    for (int f = 0; f < 2; f++) {
        gemm128<1><<<dim3(2048 / 128, BT_ / 128), 256, 0, stream>>>(
            hbuf2, 3 * C_, ff1wT, C_, f * 2048, 0, ff1_b, f * 2048,
            act, 3 * C_, C_);
        gemm64<<<dim3(C_ / 128, BT_ / 64), 256, 0, stream>>>(
            act, 3 * C_, ff2wT, F_, f * 2048, (f == 0 ? ff2_b : nullptr),
            x1, C_, x1, C_, 2048);
    }
}